// Round 1
// 484.765 us; speedup vs baseline: 7.6199x; 7.6199x over previous
//
#include <hip/hip_runtime.h>

typedef unsigned short u16;
using bf16x8 = __attribute__((ext_vector_type(8))) short;
using f32x4  = __attribute__((ext_vector_type(4))) float;

static __device__ __forceinline__ u16 f2b(float f) {
  unsigned int x = __builtin_bit_cast(unsigned int, f);
  unsigned int r = (x + 0x7fffu + ((x >> 16) & 1u)) >> 16;
  return (u16)r;
}
static __device__ __forceinline__ float fin(float x) { return (x != x) ? 0.f : x; }
static __device__ __forceinline__ float expclamp(float x) {
  return __expf(fminf(fmaxf(x, -80.f), 80.f));
}

#define SCALE 0.04419417382415922f  // 1/sqrt(512)

#define MFMA16(a, b, c) __builtin_amdgcn_mfma_f32_16x16x32_bf16((a), (b), (c), 0, 0, 0)

// global->LDS direct copy, 16B per lane. LDS dest = wave-uniform base + lane*16.
// AS casts via integer bounce (CK-style): AS(1) value == generic value; AS(3) = low 32 bits.
static __device__ __forceinline__ void glds16(const u16* g, u16* l) {
  __builtin_amdgcn_global_load_lds(
      (const __attribute__((address_space(1))) unsigned int*)(unsigned long long)(const void*)g,
      (__attribute__((address_space(3))) unsigned int*)(unsigned int)(unsigned long long)(void*)l,
      16, 0, 0);
}

// Memory plan (unchanged ws budget: exactly 33,554,432 B):
//   ws:    K bf16 [8][2048][512] @0;  Vt bf16 [8][512][2048] (V TRANSPOSED) @16.78MB
//   d_out: per fp32-row r (4096 B): [0,1024) Q bf16 row stash (stride 2048 u16),
//          [1024,1028) rdenom float (1/denom for column i=r%2048),
//          [2048,4096) read output (fp32). copy_in (LAST) overwrites [0,2048).

// ---------------- K1: QKV projection, MFMA GEMM ----------------
// C[t,n] = sum_c X[t,c]*W[n,c] + bias[n].  128x128 tile, 4 waves (2x2 of 64x64),
// BK=64, fp32->bf16 convert in staging, XOR slot swizzle (slot^ (row&7)) for
// conflict-free ds_read_b128 frags. z=0: Q->stash; z=1: K->ws; z=2: V->ws transposed.
__global__ __launch_bounds__(256) void qkv_mfma(
    const float* __restrict__ X,
    const float* __restrict__ Wq, const float* __restrict__ bq,
    const float* __restrict__ Wk, const float* __restrict__ bk,
    const float* __restrict__ Wv, const float* __restrict__ bv,
    u16* __restrict__ outq, u16* __restrict__ Kw, u16* __restrict__ Vt) {
  __shared__ __align__(16) u16 SM[16384];  // As[128][64] | Bs[128][64]; reused as Tr[128][128]
  u16* As = SM;
  u16* Bs = SM + 8192;
  const int z = blockIdx.z;
  const float* W = (z == 0) ? Wq : ((z == 1) ? Wk : Wv);
  const float* bias = (z == 0) ? bq : ((z == 1) ? bk : bv);
  const int row0 = blockIdx.x * 128;
  const int col0 = blockIdx.y * 128;
  const int tid = threadIdx.x, lane = tid & 63, w = tid >> 6;
  const int lrow = lane & 15, lg = lane >> 4;
  const int qm = w >> 1, qn = w & 1;
  const int srow = tid >> 1, sh = tid & 1;

  const f32x4 Z4 = {0.f, 0.f, 0.f, 0.f};
  f32x4 acc[4][4];
#pragma unroll
  for (int m = 0; m < 4; ++m)
#pragma unroll
    for (int n = 0; n < 4; ++n) acc[m][n] = Z4;

  const float* Xr = X + (size_t)(row0 + srow) * 512;
  const float* Wr = W + (size_t)(col0 + srow) * 512;

  for (int ks = 0; ks < 8; ++ks) {
    const int k0 = ks * 64;
    __syncthreads();
#pragma unroll
    for (int s4 = 0; s4 < 4; ++s4) {
      const int slot = sh * 4 + s4;
      const int ds = ((slot ^ (srow & 7)) << 3);
      {
        float4 f0 = *(const float4*)(Xr + k0 + slot * 8);
        float4 f1 = *(const float4*)(Xr + k0 + slot * 8 + 4);
        uint4 pk;
        pk.x = f2b(f0.x) | ((unsigned)f2b(f0.y) << 16);
        pk.y = f2b(f0.z) | ((unsigned)f2b(f0.w) << 16);
        pk.z = f2b(f1.x) | ((unsigned)f2b(f1.y) << 16);
        pk.w = f2b(f1.z) | ((unsigned)f2b(f1.w) << 16);
        *(uint4*)&As[srow * 64 + ds] = pk;
      }
      {
        float4 f0 = *(const float4*)(Wr + k0 + slot * 8);
        float4 f1 = *(const float4*)(Wr + k0 + slot * 8 + 4);
        uint4 pk;
        pk.x = f2b(f0.x) | ((unsigned)f2b(f0.y) << 16);
        pk.y = f2b(f0.z) | ((unsigned)f2b(f0.w) << 16);
        pk.z = f2b(f1.x) | ((unsigned)f2b(f1.y) << 16);
        pk.w = f2b(f1.z) | ((unsigned)f2b(f1.w) << 16);
        *(uint4*)&Bs[srow * 64 + ds] = pk;
      }
    }
    __syncthreads();
#pragma unroll
    for (int cs = 0; cs < 2; ++cs) {
      bf16x8 af[4], bfr[4];
#pragma unroll
      for (int mf = 0; mf < 4; ++mf) {
        const int r = qm * 64 + mf * 16 + lrow;
        af[mf] = *(const bf16x8*)&As[r * 64 + (((cs * 4 + lg) ^ (r & 7)) << 3)];
      }
#pragma unroll
      for (int nf = 0; nf < 4; ++nf) {
        const int r = qn * 64 + nf * 16 + lrow;
        bfr[nf] = *(const bf16x8*)&Bs[r * 64 + (((cs * 4 + lg) ^ (r & 7)) << 3)];
      }
#pragma unroll
      for (int mf = 0; mf < 4; ++mf)
#pragma unroll
        for (int nf = 0; nf < 4; ++nf)
          acc[mf][nf] = MFMA16(af[mf], bfr[nf], acc[mf][nf]);
    }
  }

  // D layout (verified): col = lane&15, row = (lane>>4)*4 + reg.
  if (z < 2) {
    u16* O = (z == 0) ? outq : Kw;
    const int ldo = (z == 0) ? 2048 : 512;
#pragma unroll
    for (int mf = 0; mf < 4; ++mf)
#pragma unroll
      for (int nf = 0; nf < 4; ++nf) {
        const int C = col0 + qn * 64 + nf * 16 + lrow;
        const float bb = bias[C];
#pragma unroll
        for (int r = 0; r < 4; ++r) {
          const int R = row0 + qm * 64 + mf * 16 + lg * 4 + r;
          O[(size_t)R * ldo + C] = f2b(fin(acc[mf][nf][r] + bb));
        }
      }
  } else {
    // V: transpose tile through LDS, store Vt[b][v][t] coalesced.
    __syncthreads();
    u16* Tr = SM;  // [128][128]
#pragma unroll
    for (int mf = 0; mf < 4; ++mf)
#pragma unroll
      for (int nf = 0; nf < 4; ++nf) {
        const int vl = qn * 64 + nf * 16 + lrow;
        const float bb = bias[col0 + vl];
#pragma unroll
        for (int r = 0; r < 4; ++r) {
          const int tl = qm * 64 + mf * 16 + lg * 4 + r;
          Tr[vl * 128 + tl] = f2b(fin(acc[mf][nf][r] + bb));
        }
      }
    __syncthreads();
    const int vl = tid >> 1, part = tid & 1;
    const int bI = row0 >> 11;
    u16* dst = Vt + (size_t)(bI * 512 + col0 + vl) * 2048 + (row0 & 2047) + part * 64;
    const u16* sp = &Tr[vl * 128 + part * 64];
#pragma unroll
    for (int q = 0; q < 8; ++q)
      *(uint4*)(dst + q * 8) = *(const uint4*)(sp + q * 8);
  }
}

// ---------------- K2: column denominators via MFMA ----------------
// rdenom[i] = 1 / sum_{j>=i} exp(S[j,i]*SCALE).  Swapped QK^T: D = mfma(K_i, Q_j)
// -> D[m=i-local][n=j-local].  BI=32, K frags in registers, Q frags direct from
// the stash.  Paired i-tiles (x, 63-x) => constant 2080-row sweep per block.
__global__ __launch_bounds__(256) void denom_mfma(
    const u16* __restrict__ Qs, const u16* __restrict__ Kw, float* __restrict__ rdn) {
  __shared__ float red[4][32];
  const int b = blockIdx.y, x = blockIdx.x;
  const int tid = threadIdx.x, lane = tid & 63, w = tid >> 6;
  const int lrow = lane & 15, lg = lane >> 4;
  for (int pass = 0; pass < 2; ++pass) {
    const int it = pass ? (63 - x) : x;
    const int i0 = it * 32;
    bf16x8 Kf[2][16];
#pragma unroll
    for (int f = 0; f < 2; ++f) {
      const u16* kr = Kw + (size_t)(b * 2048 + i0 + f * 16 + lrow) * 512;
#pragma unroll
      for (int cs = 0; cs < 16; ++cs) Kf[f][cs] = *(const bf16x8*)(kr + cs * 32 + lg * 8);
    }
    float ps[2][4];
#pragma unroll
    for (int f = 0; f < 2; ++f)
#pragma unroll
      for (int r = 0; r < 4; ++r) ps[f][r] = 0.f;
    for (int jt = 2 * it + w; jt < 128; jt += 4) {
      const int j0 = jt * 16;
      const u16* qr = Qs + (size_t)(b * 2048 + j0 + lrow) * 2048;
      bf16x8 Qf[16];
#pragma unroll
      for (int cs = 0; cs < 16; ++cs) Qf[cs] = *(const bf16x8*)(qr + cs * 32 + lg * 8);
#pragma unroll
      for (int f = 0; f < 2; ++f) {
        f32x4 s = {0.f, 0.f, 0.f, 0.f};
#pragma unroll
        for (int cs = 0; cs < 16; ++cs) s = MFMA16(Kf[f][cs], Qf[cs], s);
        const int j = j0 + lrow;
#pragma unroll
        for (int r = 0; r < 4; ++r) {
          const int i = i0 + f * 16 + lg * 4 + r;
          if (j >= i) ps[f][r] += expclamp(s[r] * SCALE);
        }
      }
    }
#pragma unroll
    for (int f = 0; f < 2; ++f)
#pragma unroll
      for (int r = 0; r < 4; ++r) {
        float v = ps[f][r];
        v += __shfl_xor(v, 1); v += __shfl_xor(v, 2);
        v += __shfl_xor(v, 4); v += __shfl_xor(v, 8);
        if (lrow == 0) red[w][f * 16 + lg * 4 + r] = v;
      }
    __syncthreads();
    if (tid < 32) {
      const float d = red[0][tid] + red[1][tid] + red[2][tid] + red[3][tid];
      rdn[(size_t)(b * 2048 + i0 + tid) * 1024 + 256] = 1.0f / fmaxf(d, 1e-30f);
    }
    __syncthreads();
  }
}

// ---------------- K3: fused causal read, flash-style MFMA ----------------
// Block (jt,b): 64 q-rows, 4 waves x 16 j.  Q in regs (16 frags).  Per 32-i window:
// stage K[32][512] + Vt[512][32] via glds (pre-swizzled source), QK^T MFMA,
// P = exp(S*SCALE)*rdenom[i] -> bf16 via per-wave LDS, PV MFMA into O[32] f32x4.
// Double-buffered with raw s_barrier + counted vmcnt (16 glds + 2 rdenom = 18).
__global__ __launch_bounds__(256) void read_mfma(
    const u16* __restrict__ Qs, const u16* __restrict__ Kw, const u16* __restrict__ Vt,
    const float* __restrict__ rdn, float* __restrict__ outf) {
  __shared__ __align__(16) u16 KB[2][16384];  // [32 i][512 c], slot^=(row&7)
  __shared__ __align__(16) u16 VB[2][16384];  // [512 v][32 i], slot^=((v>>1)&3)
  __shared__ __align__(16) u16 PB[4][640];    // per-wave P[16 j][32 i], stride 40 u16
  const int jt = blockIdx.x, b = blockIdx.y;
  const int j0 = jt * 64;
  const int tid = threadIdx.x, lane = tid & 63, w = tid >> 6;
  const int lrow = lane & 15, lg = lane >> 4;
  const int NW = 2 * (jt + 1);

  bf16x8 Qf[16];
  {
    const u16* qr = Qs + (size_t)(b * 2048 + j0 + w * 16 + lrow) * 2048;
#pragma unroll
    for (int cs = 0; cs < 16; ++cs) Qf[cs] = *(const bf16x8*)(qr + cs * 32 + lg * 8);
  }
  const f32x4 Z4 = {0.f, 0.f, 0.f, 0.f};
  f32x4 O[32];
#pragma unroll
  for (int vt = 0; vt < 32; ++vt) O[vt] = Z4;
  u16* pw = &PB[w][0];

  const size_t kbase = (size_t)b * 2048 * 512;
  const size_t vbase = (size_t)b * 512 * 2048;
  auto stage = [&](int buf, int i0) {
#pragma unroll
    for (int p = 0; p < 8; ++p) {
      const int row = p * 4 + w;
      glds16(Kw + kbase + (size_t)(i0 + row) * 512 + ((lane ^ (row & 7)) << 3),
             &KB[buf][row * 512]);
    }
#pragma unroll
    for (int p = 0; p < 8; ++p) {
      const int q = p * 4 + w;
      const int vloc = q * 16 + (lane >> 2);
      const int s = (lane & 3) ^ ((vloc >> 1) & 3);
      glds16(Vt + vbase + (size_t)vloc * 2048 + i0 + s * 8,
             &VB[buf][q * 512]);
    }
  };

  stage(0, 0);
  for (int win = 0; win < NW; ++win) {
    const int cur = win & 1;
    const int i0 = win * 32;
    const float rd0 = rdn[(size_t)(b * 2048 + i0 + lrow) * 1024 + 256];
    const float rd1 = rdn[(size_t)(b * 2048 + i0 + 16 + lrow) * 1024 + 256];
    if (win + 1 < NW) {
      stage(cur ^ 1, i0 + 32);
      // drain current window's 16 glds; keep next 16 + 2 rdenom in flight
      asm volatile("s_waitcnt vmcnt(18)" ::: "memory");
    } else {
      asm volatile("s_waitcnt vmcnt(2)" ::: "memory");
    }
    __builtin_amdgcn_s_barrier();

    const u16* kb = &KB[cur][0];
    const u16* vb = &VB[cur][0];
    f32x4 s0 = Z4, s1 = Z4;
#pragma unroll
    for (int cs = 0; cs < 16; ++cs) {
      const int sl = cs * 4 + lg;
      bf16x8 k0 = *(const bf16x8*)(kb + lrow * 512 + ((sl ^ (lrow & 7)) << 3));
      bf16x8 k1 = *(const bf16x8*)(kb + (16 + lrow) * 512 + ((sl ^ (lrow & 7)) << 3));
      s0 = MFMA16(Qf[cs], k0, s0);
      s1 = MFMA16(Qf[cs], k1, s1);
    }
    const int jb = j0 + w * 16 + lg * 4;
#pragma unroll
    for (int r = 0; r < 4; ++r) {
      const int jj = jb + r;
      const float e0 = (i0 + lrow <= jj) ? expclamp(s0[r] * SCALE) * rd0 : 0.f;
      const float e1 = (i0 + 16 + lrow <= jj) ? expclamp(s1[r] * SCALE) * rd1 : 0.f;
      pw[(lg * 4 + r) * 40 + lrow] = f2b(e0);
      pw[(lg * 4 + r) * 40 + 16 + lrow] = f2b(e1);
    }
    asm volatile("s_waitcnt lgkmcnt(0)" ::: "memory");
    const bf16x8 pa = *(const bf16x8*)(pw + lrow * 40 + lg * 8);
#pragma unroll
    for (int vt = 0; vt < 32; ++vt) {
      const int vloc = vt * 16 + lrow;
      const bf16x8 vf = *(const bf16x8*)(vb + vloc * 32 + ((lg ^ ((vloc >> 1) & 3)) << 3));
      O[vt] = MFMA16(pa, vf, O[vt]);
    }
    __builtin_amdgcn_s_barrier();  // all reads of buf[cur] done before it is restaged
  }

#pragma unroll
  for (int vt = 0; vt < 32; ++vt) {
    const int v = vt * 16 + lrow;
#pragma unroll
    for (int r = 0; r < 4; ++r) {
      const int jj = j0 + w * 16 + lg * 4 + r;
      outf[(size_t)(b * 2048 + jj) * 1024 + 512 + v] = fin(O[vt][r]);
    }
  }
}

// ---------------- K4: passthrough fp32 X -> out[:,0:512] (LAST) ----------------
__global__ __launch_bounds__(256) void copy_in_kernel(
    const float* __restrict__ X, float* __restrict__ outf) {
  size_t idx = (size_t)blockIdx.x * 256 + threadIdx.x;
  size_t row = idx >> 7;
  int c = (int)(idx & 127) * 4;
  *(float4*)&outf[row * 1024 + c] = *(const float4*)&X[row * 512 + c];
}

extern "C" void kernel_launch(void* const* d_in, const int* in_sizes, int n_in,
                              void* d_out, int out_size, void* d_ws, size_t ws_size,
                              hipStream_t stream) {
  const float* X  = (const float*)d_in[0];
  const float* Wq = (const float*)d_in[1];
  const float* bq = (const float*)d_in[2];
  const float* Wk = (const float*)d_in[3];
  const float* bk = (const float*)d_in[4];
  const float* Wv = (const float*)d_in[5];
  const float* bv = (const float*)d_in[6];

  char* ws = (char*)d_ws;
  const size_t SZ = (size_t)16384 * 512 * sizeof(u16);
  u16* Kw = (u16*)(ws);
  u16* Vt = (u16*)(ws + SZ);

  qkv_mfma<<<dim3(128, 4, 3), 256, 0, stream>>>(X, Wq, bq, Wk, bk, Wv, bv,
                                                (u16*)d_out, Kw, Vt);
  denom_mfma<<<dim3(32, 8), 256, 0, stream>>>((const u16*)d_out, Kw, (float*)d_out);
  read_mfma<<<dim3(32, 8), 256, 0, stream>>>((const u16*)d_out, Kw, Vt,
                                             (const float*)d_out, (float*)d_out);
  copy_in_kernel<<<8192, 256, 0, stream>>>(X, (float*)d_out);
}